// Round 13
// baseline (76.192 us; speedup 1.0000x reference)
//
#include <hip/hip_runtime.h>
#include <math.h>

// Geometry (fixed by the reference).
#define HS    2048            // hidden size (output columns)
#define DIN   2048            // input dim (reduction length)
#define RPS   32              // rows per slab
#define NSLAB (DIN / RPS)     // 64 slabs per matrix
#define NBLK  256             // 4 mats x 64 slabs; 1 block/CU, 1 generation
#define NRED  64              // reducer blocks (ticket-selected)

// Native Clang vector type: __builtin_nontemporal_load accepts these.
typedef float float4n __attribute__((ext_vector_type(4)));

// ---------------------------------------------------------------------------
// Algebra: cell = f*c0 + dot(i,c); dot(i,c) is a scalar broadcast and the
// mean/std normalization cancels constant shifts, so
//   h = o * tanh((f*c0 - mean(f*c0)) / (std(f*c0, ddof=1) + 1e-5)).
// The i and c gates (w_xi, w_hi, w_xc, w_hc, b_i, b_c) are dead.
//
// SINGLE fused kernel (saves one graph node + full-grid drain vs r12):
//  Phase A (all 256 blocks): r12's contiguous-slab GEMV. Block b: mat=b>>6,
//    slab=b&63 -> rows [slab*32, slab*32+32), one contiguous 256 KB nt
//    stream, thread t owns col quads t*4 / 1024+t*4, coalesced 8 KB
//    partial-row store to zp[256][2048] (2 MB, pure overwrite).
//  Ticket 1: atomicInc(cnt, 255). Steady-state: counter starts each call at
//    255 (self-stabilizing after the first wrap; poison-robust), so temporal
//    rank r sees old==r-1 (r=0 sees 255/poison). Ranks 192..255 (old in
//    [191,254]) become reducers; rank 255 (old==254) needs no wait.
//  Phase B (64 reducers): spin until cnt==255 (monotone after own inc ->
//    no stale race), then r12's stage-2 slice (slice = old-191): reduce 128
//    partial rows per gate column-group, sigmoid, write vbuf/obuf.
//  Ticket 2: atomicInc(cnt2, 63); old2==62 -> last reducer finalizes
//    mean/std/tanh and writes out. All tickets are exact-count-per-call ->
//    self-stabilizing for ANY initial memory contents.
// ---------------------------------------------------------------------------
__global__ __launch_bounds__(256) void lstm_fused(
        const float* __restrict__ x,    const float* __restrict__ h0,
        const float* __restrict__ w_xf, const float* __restrict__ w_hf,
        const float* __restrict__ w_xo, const float* __restrict__ w_ho,
        const float* __restrict__ b_f,  const float* __restrict__ b_o,
        const float* __restrict__ c0,   float* __restrict__ out,
        float* __restrict__ zp /* [NBLK][HS] */,
        float* __restrict__ vbuf, float* __restrict__ obuf,
        unsigned* __restrict__ cnt, unsigned* __restrict__ cnt2) {
    const int b = blockIdx.x;
    const int t = threadIdx.x;

    // ================= Phase A: GEMV slab =================
    {
        const int mat  = b >> 6;             // 0:w_xf 1:w_hf 2:w_xo 3:w_ho
        const int slab = b & (NSLAB - 1);
        const float* W   = (mat == 0) ? w_xf : (mat == 1) ? w_hf
                         : (mat == 2) ? w_xo : w_ho;
        const float* vec = (mat & 1) ? h0 : x;

        const int r0 = slab * RPS;
        const float4n* wp =
            reinterpret_cast<const float4n*>(W + (size_t)r0 * HS) + t;

        float4n a0 = {0.f, 0.f, 0.f, 0.f};
        float4n a1 = {0.f, 0.f, 0.f, 0.f};
        float4n a2 = {0.f, 0.f, 0.f, 0.f};
        float4n a3 = {0.f, 0.f, 0.f, 0.f};
#pragma unroll
        for (int r = 0; r < RPS; r += 2) {
            const float s0 = vec[r0 + r];    // block-uniform -> scalar load
            const float s1 = vec[r0 + r + 1];
            const float4n w00 = __builtin_nontemporal_load(wp + (size_t)r * (HS / 4));
            const float4n w01 = __builtin_nontemporal_load(wp + (size_t)r * (HS / 4) + 256);
            const float4n w10 = __builtin_nontemporal_load(wp + (size_t)(r + 1) * (HS / 4));
            const float4n w11 = __builtin_nontemporal_load(wp + (size_t)(r + 1) * (HS / 4) + 256);
            a0 += s0 * w00;
            a1 += s0 * w01;
            a2 += s1 * w10;
            a3 += s1 * w11;
        }
        const float4n q0 = a0 + a2;
        const float4n q1 = a1 + a3;
        float4n* zrow = reinterpret_cast<float4n*>(zp + (size_t)b * HS);
        zrow[t]       = q0;
        zrow[256 + t] = q1;
    }

    // ================= Ticket 1: rank assignment =================
    __shared__ unsigned shOld;
    __threadfence();                         // release zp stores (all threads)
    __syncthreads();
    if (t == 0) shOld = atomicInc(cnt, NBLK - 1u);
    __syncthreads();
    const unsigned old = shOld;

    // reducers: temporal ranks 192..255  <=>  old in [NBLK-65, NBLK-2]
    if (old < NBLK - 65u || old > NBLK - 2u) return;
    const int slice = (int)(old - (NBLK - 65u));   // 0..63

    // spin until all 256 increments landed (cnt stores rank; final = 255)
    if (t == 0) {
        while (atomicAdd(cnt, 0u) != NBLK - 1u) __builtin_amdgcn_s_sleep(1);
    }
    __syncthreads();
    __threadfence();                         // acquire zp (all threads)

    // ================= Phase B: stage-2 slice =================
    const int g  = slice >> 5;               // 0 = f, 1 = o
    const int cg = slice & 31;               // 64-col group
    const int fg = t & 15;                   // float4 quad within group
    const int ph = t >> 4;                   // row phase 0..15

    __shared__ float4 part[4][16];
    __shared__ unsigned lastFlag;

    const int colq = cg * 64 + fg * 4;

    float4 acc0 = make_float4(0.f, 0.f, 0.f, 0.f);
    float4 acc1 = make_float4(0.f, 0.f, 0.f, 0.f);
#pragma unroll
    for (int k = 0; k < 8; k += 2) {
        const int row0 = g * 128 + ph + (k << 4);
        const int row1 = g * 128 + ph + ((k + 1) << 4);
        const float4 p0 = *reinterpret_cast<const float4*>(
            zp + (size_t)row0 * HS + colq);
        const float4 p1 = *reinterpret_cast<const float4*>(
            zp + (size_t)row1 * HS + colq);
        acc0.x += p0.x;  acc0.y += p0.y;  acc0.z += p0.z;  acc0.w += p0.w;
        acc1.x += p1.x;  acc1.y += p1.y;  acc1.z += p1.z;  acc1.w += p1.w;
    }
    float4 s4;
    s4.x = acc0.x + acc1.x;  s4.y = acc0.y + acc1.y;
    s4.z = acc0.z + acc1.z;  s4.w = acc0.w + acc1.w;

#pragma unroll
    for (int m = 16; m <= 32; m <<= 1) {
        s4.x += __shfl_xor(s4.x, m);
        s4.y += __shfl_xor(s4.y, m);
        s4.z += __shfl_xor(s4.z, m);
        s4.w += __shfl_xor(s4.w, m);
    }
    if ((t & 63) < 16) part[t >> 6][fg] = s4;
    __syncthreads();

    if (t < 16) {
        float4 z;
        z.x = (part[0][t].x + part[1][t].x) + (part[2][t].x + part[3][t].x);
        z.y = (part[0][t].y + part[1][t].y) + (part[2][t].y + part[3][t].y);
        z.z = (part[0][t].z + part[1][t].z) + (part[2][t].z + part[3][t].z);
        z.w = (part[0][t].w + part[1][t].w) + (part[2][t].w + part[3][t].w);
        const int col = cg * 64 + t * 4;
        if (g == 0) {
            const float4 bf = *reinterpret_cast<const float4*>(b_f + col);
            const float4 cv = *reinterpret_cast<const float4*>(c0 + col);
            float4 r;
            r.x = cv.x / (1.f + expf(-(z.x + bf.x)));
            r.y = cv.y / (1.f + expf(-(z.y + bf.y)));
            r.z = cv.z / (1.f + expf(-(z.z + bf.z)));
            r.w = cv.w / (1.f + expf(-(z.w + bf.w)));
            *reinterpret_cast<float4*>(vbuf + col) = r;   // v = sig(zf)*c0
        } else {
            const float4 bo = *reinterpret_cast<const float4*>(b_o + col);
            float4 r;
            r.x = 1.f / (1.f + expf(-(z.x + bo.x)));
            r.y = 1.f / (1.f + expf(-(z.y + bo.y)));
            r.z = 1.f / (1.f + expf(-(z.z + bo.z)));
            r.w = 1.f / (1.f + expf(-(z.w + bo.w)));
            *reinterpret_cast<float4*>(obuf + col) = r;   // o gate
        }
    }

    // ================= Ticket 2: last reducer finalizes =================
    __threadfence();                         // release vbuf/obuf (all threads)
    __syncthreads();
    if (t == 0) {
        const unsigned old2 = atomicInc(cnt2, NRED - 1u);
        lastFlag = (old2 == NRED - 2u);      // temporally-last reducer
    }
    __syncthreads();
    if (!lastFlag) return;
    __threadfence();                         // acquire vbuf/obuf

    const int lane = t & 63;
    const int wv   = t >> 6;
    __shared__ float red[2][4];

    float v[8], og[8];
    float lsum = 0.f;
#pragma unroll
    for (int e = 0; e < 8; ++e) {
        const int j = t * 8 + e;
        v[e]  = vbuf[j];
        og[e] = obuf[j];
        lsum += v[e];
    }
#pragma unroll
    for (int s = 32; s > 0; s >>= 1) lsum += __shfl_down(lsum, s);
    if (lane == 0) red[0][wv] = lsum;
    __syncthreads();
    const float mean = (red[0][0] + red[0][1] + red[0][2] + red[0][3]) * (1.f / 2048.f);

    float lss = 0.f;
#pragma unroll
    for (int e = 0; e < 8; ++e) {
        const float d = v[e] - mean;
        lss += d * d;
    }
#pragma unroll
    for (int s = 32; s > 0; s >>= 1) lss += __shfl_down(lss, s);
    if (lane == 0) red[1][wv] = lss;
    __syncthreads();
    const float var = (red[1][0] + red[1][1] + red[1][2] + red[1][3]) * (1.f / 2047.f);
    const float inv = 1.f / (sqrtf(var) + 1e-5f);

#pragma unroll
    for (int e = 0; e < 8; ++e) {
        const int j = t * 8 + e;
        out[j] = og[e] * tanhf((v[e] - mean) * inv);
    }
}

extern "C" void kernel_launch(void* const* d_in, const int* in_sizes, int n_in,
                              void* d_out, int out_size, void* d_ws, size_t ws_size,
                              hipStream_t stream) {
    // setup_inputs order:
    // 0:x 1:w_xi 2:w_xf 3:w_xo 4:w_xc 5:w_hi 6:w_hf 7:w_ho 8:w_hc
    // 9:b_i 10:b_f 11:b_o 12:b_c 13:h0 14:c0
    const float* x    = (const float*)d_in[0];
    const float* w_xf = (const float*)d_in[2];
    const float* w_xo = (const float*)d_in[3];
    const float* w_hf = (const float*)d_in[6];
    const float* w_ho = (const float*)d_in[7];
    const float* b_f  = (const float*)d_in[10];
    const float* b_o  = (const float*)d_in[11];
    const float* h0   = (const float*)d_in[13];
    const float* c0   = (const float*)d_in[14];
    float* out = (float*)d_out;

    float* zp      = (float*)d_ws;                 // [256][2048] fp32 = 2 MB
    float* vbuf    = zp + (size_t)NBLK * HS;       // 2048 fp32
    float* obuf    = vbuf + HS;                    // 2048 fp32
    unsigned* cnt  = (unsigned*)(obuf + HS);       // ticket 1 (any init ok)
    unsigned* cnt2 = cnt + 1;                      // ticket 2 (any init ok)

    lstm_fused<<<NBLK, 256, 0, stream>>>(x, h0, w_xf, w_hf, w_xo, w_ho,
                                         b_f, b_o, c0, out, zp, vbuf, obuf,
                                         cnt, cnt2);
}

// Round 14
// 20.730 us; speedup vs baseline: 3.6754x; 3.6754x over previous
//
#include <hip/hip_runtime.h>
#include <math.h>

// Geometry (fixed by the reference).
#define HS    2048            // hidden size (output columns)
#define DIN   2048            // input dim (reduction length)
#define RPS   32              // rows per slab
#define NSLAB (DIN / RPS)     // 64 slabs per matrix
#define NBLK1 256             // 4 mats x 64 slabs; 1 block/CU, 1 generation
#define NBLK2 64              // stage-2 blocks

// Native Clang vector type: __builtin_nontemporal_load accepts these
// (it rejects HIP_vector_type<float,4>*).
typedef float float4n __attribute__((ext_vector_type(4)));

// ---------------------------------------------------------------------------
// REVERT to r12 (best verified: 20.9 us). r13's single-kernel fusion proved
// the 2-node structure is optimal: intra-kernel grid sync on 8 non-coherent
// XCD L2s costs ~55 us (fences -> L2 writeback/invalidate per block + spin
// on a contended atomic line), vs ~1.5 us for a kernel boundary.
//
// Algebra: cell = f*c0 + dot(i,c); dot(i,c) is a scalar broadcast and the
// mean/std normalization cancels constant shifts, so
//   h = o * tanh((f*c0 - mean(f*c0)) / (std(f*c0, ddof=1) + 1e-5)).
// The i and c gates (w_xi, w_hi, w_xc, w_hc, b_i, b_c) are dead.
//
// Stage 1: contiguous-slab GEMV. Block b: mat = b>>6, slab = b&63 -> rows
// [slab*32, slab*32+32), full 2048-col width: one contiguous 256 KB nt
// stream per block. Thread t owns fixed col quads t*4 and 1024+t*4 -> 64
// independent nt float4 loads, every wave-instruction 1 KB contiguous.
// 256 blocks = 1/CU, single generation. 4 rotating accumulators; one
// coalesced 8 KB partial-row store. zp [256][2048] = 2 MB, pure overwrite
// (poison-proof), no atomics, no LDS.
// ---------------------------------------------------------------------------
__global__ __launch_bounds__(256) void gemv_slab(
        const float* __restrict__ x,    const float* __restrict__ h0,
        const float* __restrict__ w_xf, const float* __restrict__ w_hf,
        const float* __restrict__ w_xo, const float* __restrict__ w_ho,
        float* __restrict__ zp /* [NBLK1][HS] */) {
    const int b    = blockIdx.x;
    const int t    = threadIdx.x;
    const int mat  = b >> 6;                 // 0:w_xf 1:w_hf 2:w_xo 3:w_ho
    const int slab = b & (NSLAB - 1);

    const float* W   = (mat == 0) ? w_xf : (mat == 1) ? w_hf
                     : (mat == 2) ? w_xo : w_ho;
    const float* vec = (mat & 1) ? h0 : x;

    const int r0 = slab * RPS;
    const float4n* wp = reinterpret_cast<const float4n*>(W + (size_t)r0 * HS) + t;

    float4n a0 = {0.f, 0.f, 0.f, 0.f};  // quad0, even rows
    float4n a1 = {0.f, 0.f, 0.f, 0.f};  // quad1, even rows
    float4n a2 = {0.f, 0.f, 0.f, 0.f};  // quad0, odd rows
    float4n a3 = {0.f, 0.f, 0.f, 0.f};  // quad1, odd rows
#pragma unroll
    for (int r = 0; r < RPS; r += 2) {
        const float s0 = vec[r0 + r];        // block-uniform -> scalar load
        const float s1 = vec[r0 + r + 1];
        // non-temporal: single-use stream, bypass cache allocation
        const float4n w00 = __builtin_nontemporal_load(wp + (size_t)r * (HS / 4));
        const float4n w01 = __builtin_nontemporal_load(wp + (size_t)r * (HS / 4) + 256);
        const float4n w10 = __builtin_nontemporal_load(wp + (size_t)(r + 1) * (HS / 4));
        const float4n w11 = __builtin_nontemporal_load(wp + (size_t)(r + 1) * (HS / 4) + 256);
        a0 += s0 * w00;
        a1 += s0 * w01;
        a2 += s1 * w10;
        a3 += s1 * w11;
    }
    const float4n q0 = a0 + a2;
    const float4n q1 = a1 + a3;
    float4n* zrow = reinterpret_cast<float4n*>(zp + (size_t)b * HS);
    zrow[t]       = q0;   // cols t*4 ..
    zrow[256 + t] = q1;   // cols 1024 + t*4 ..
}

// ---------------------------------------------------------------------------
// Stage 2: reduce 128 partial rows per gate (zp rows [g*128, g*128+128)),
// float4 loads, sigmoid, then last-block ticket -> mean/std -> output.
//   block bb: gate g = bb>>5, col group cg = bb&31 (64 cols).
//   thread t: fg = t&15 (float4 quad), ph = t>>4 (16 phases); sums rows
//   g*128 + ph + 16k, k=0..7 (8 independent float4 loads, L2-hot 2 MB).
// vbuf/obuf fully overwritten each call; atomicInc-wrap ticket selects
// exactly one block per call for ANY initial counter value (0xAA poison ok).
// ---------------------------------------------------------------------------
__global__ __launch_bounds__(256) void reduce_fin(
        const float* __restrict__ zp,
        const float* __restrict__ b_f, const float* __restrict__ b_o,
        const float* __restrict__ c0,  float* __restrict__ out,
        float* __restrict__ vbuf, float* __restrict__ obuf,
        unsigned* __restrict__ cnt) {
    const int t  = threadIdx.x;
    const int g  = blockIdx.x >> 5;          // 0 = f, 1 = o
    const int cg = blockIdx.x & 31;          // 64-col group
    const int fg = t & 15;                   // float4 quad within group
    const int ph = t >> 4;                   // row phase 0..15

    __shared__ float4 part[4][16];
    __shared__ unsigned lastFlag;

    const int colq = cg * 64 + fg * 4;       // this thread's column quad

    float4 acc0 = make_float4(0.f, 0.f, 0.f, 0.f);
    float4 acc1 = make_float4(0.f, 0.f, 0.f, 0.f);
#pragma unroll
    for (int k = 0; k < 8; k += 2) {
        const int row0 = g * 128 + ph + (k << 4);
        const int row1 = g * 128 + ph + ((k + 1) << 4);
        const float4 p0 = *reinterpret_cast<const float4*>(
            zp + (size_t)row0 * HS + colq);
        const float4 p1 = *reinterpret_cast<const float4*>(
            zp + (size_t)row1 * HS + colq);
        acc0.x += p0.x;  acc0.y += p0.y;  acc0.z += p0.z;  acc0.w += p0.w;
        acc1.x += p1.x;  acc1.y += p1.y;  acc1.z += p1.z;  acc1.w += p1.w;
    }
    float4 s4;
    s4.x = acc0.x + acc1.x;  s4.y = acc0.y + acc1.y;
    s4.z = acc0.z + acc1.z;  s4.w = acc0.w + acc1.w;

    // reduce the 4 in-wave phases (lane l, l^16, l^32 hold adjacent ph)
#pragma unroll
    for (int m = 16; m <= 32; m <<= 1) {
        s4.x += __shfl_xor(s4.x, m);
        s4.y += __shfl_xor(s4.y, m);
        s4.z += __shfl_xor(s4.z, m);
        s4.w += __shfl_xor(s4.w, m);
    }
    if ((t & 63) < 16) part[t >> 6][fg] = s4;
    __syncthreads();

    if (t < 16) {
        float4 z;
        z.x = (part[0][t].x + part[1][t].x) + (part[2][t].x + part[3][t].x);
        z.y = (part[0][t].y + part[1][t].y) + (part[2][t].y + part[3][t].y);
        z.z = (part[0][t].z + part[1][t].z) + (part[2][t].z + part[3][t].z);
        z.w = (part[0][t].w + part[1][t].w) + (part[2][t].w + part[3][t].w);
        const int col = cg * 64 + t * 4;
        if (g == 0) {
            const float4 bf = *reinterpret_cast<const float4*>(b_f + col);
            const float4 cv = *reinterpret_cast<const float4*>(c0 + col);
            float4 r;
            r.x = cv.x / (1.f + expf(-(z.x + bf.x)));
            r.y = cv.y / (1.f + expf(-(z.y + bf.y)));
            r.z = cv.z / (1.f + expf(-(z.z + bf.z)));
            r.w = cv.w / (1.f + expf(-(z.w + bf.w)));
            *reinterpret_cast<float4*>(vbuf + col) = r;   // v = sig(zf)*c0
        } else {
            const float4 bo = *reinterpret_cast<const float4*>(b_o + col);
            float4 r;
            r.x = 1.f / (1.f + expf(-(z.x + bo.x)));
            r.y = 1.f / (1.f + expf(-(z.y + bo.y)));
            r.z = 1.f / (1.f + expf(-(z.z + bo.z)));
            r.w = 1.f / (1.f + expf(-(z.w + bo.w)));
            *reinterpret_cast<float4*>(obuf + col) = r;   // o gate
        }
    }
    __syncthreads();

    // ---- last-block ticket (device scope; robust to any initial cnt) ----
    if (t == 0) {
        __threadfence();                          // release vbuf/obuf writes
        const unsigned old = atomicInc(cnt, NBLK2 - 1u);
        lastFlag = (old == NBLK2 - 2u);           // exactly one block per call
    }
    __syncthreads();
    if (!lastFlag) return;
    __threadfence();                              // acquire

    // ---- finalize: h = o * tanh((v - mean) / (std_ddof1 + 1e-5)) ----
    const int lane = t & 63;
    const int wv   = t >> 6;
    __shared__ float red[2][4];

    float v[8], og[8];
    float lsum = 0.f;
#pragma unroll
    for (int e = 0; e < 8; ++e) {
        const int j = t * 8 + e;
        v[e]  = vbuf[j];
        og[e] = obuf[j];
        lsum += v[e];
    }
#pragma unroll
    for (int s = 32; s > 0; s >>= 1) lsum += __shfl_down(lsum, s);
    if (lane == 0) red[0][wv] = lsum;
    __syncthreads();
    const float mean = (red[0][0] + red[0][1] + red[0][2] + red[0][3]) * (1.f / 2048.f);

    float lss = 0.f;
#pragma unroll
    for (int e = 0; e < 8; ++e) {
        const float d = v[e] - mean;
        lss += d * d;
    }
#pragma unroll
    for (int s = 32; s > 0; s >>= 1) lss += __shfl_down(lss, s);
    if (lane == 0) red[1][wv] = lss;
    __syncthreads();
    const float var = (red[1][0] + red[1][1] + red[1][2] + red[1][3]) * (1.f / 2047.f);
    const float inv = 1.f / (sqrtf(var) + 1e-5f);

#pragma unroll
    for (int e = 0; e < 8; ++e) {
        const int j = t * 8 + e;
        out[j] = og[e] * tanhf((v[e] - mean) * inv);
    }
}

extern "C" void kernel_launch(void* const* d_in, const int* in_sizes, int n_in,
                              void* d_out, int out_size, void* d_ws, size_t ws_size,
                              hipStream_t stream) {
    // setup_inputs order:
    // 0:x 1:w_xi 2:w_xf 3:w_xo 4:w_xc 5:w_hi 6:w_hf 7:w_ho 8:w_hc
    // 9:b_i 10:b_f 11:b_o 12:b_c 13:h0 14:c0
    const float* x    = (const float*)d_in[0];
    const float* w_xf = (const float*)d_in[2];
    const float* w_xo = (const float*)d_in[3];
    const float* w_hf = (const float*)d_in[6];
    const float* w_ho = (const float*)d_in[7];
    const float* b_f  = (const float*)d_in[10];
    const float* b_o  = (const float*)d_in[11];
    const float* h0   = (const float*)d_in[13];
    const float* c0   = (const float*)d_in[14];
    float* out = (float*)d_out;

    float* zp     = (float*)d_ws;                  // [256][2048] fp32 = 2 MB
    float* vbuf   = zp + (size_t)NBLK1 * HS;       // 2048 fp32
    float* obuf   = vbuf + HS;                     // 2048 fp32
    unsigned* cnt = (unsigned*)(obuf + HS);        // ticket (any init ok)

    gemv_slab<<<NBLK1, 256, 0, stream>>>(x, h0, w_xf, w_hf, w_xo, w_ho, zp);
    reduce_fin<<<NBLK2, 256, 0, stream>>>(zp, b_f, b_o, c0, out, vbuf, obuf, cnt);
}